// Round 6
// baseline (241.780 us; speedup 1.0000x reference)
//
#include <hip/hip_runtime.h>

// DynamicConv2d: GAP->MLP->softmax routing, Wdyn = sum_k a_k * bank_k,
// then per-sample 3x3 conv (pad 1) = per-sample GEMM M=256,N=3136,K=1152.
// R11: (1) k_conv MFMA shape 16x16x32 -> 32x32x16 (same LDS traffic, same
// acc regs, ~+12% pipe ceiling per m06/m119, half the MFMA issue slots);
// (2) all 8 staging loads consolidated at the tile switch (vmcnt(8), B gets
// a full tile of flight time, mid-tile is pure compute); generic 18-tile
// loop. (3) k_xpose: bf16 LDS (stride 132) + ushort4 LDS reads in the
// output loop + GAP from bf16 (err ~1e-4, threshold 2.6e-2). k_mlp/k_wdyn
// unchanged.

#define CIN    128
#define COUT   256
#define KEXP   8
#define HIDDEN 32
#define B_     32
#define H_     56
#define W_     56
#define HW     3136
#define HP     58      // 1 + 56 + 1 halo rows
#define WP     58      // 1 + 56 + 1 halo cols
#define KK     1152    // 9 * 128, order (kh*3+kw)*128 + cin

typedef float  v4f  __attribute__((ext_vector_type(4)));
typedef float  v16f __attribute__((ext_vector_type(16)));
typedef __bf16 v8bf __attribute__((ext_vector_type(8)));

__device__ __forceinline__ unsigned short f2bf(float x) {
  unsigned int u = __float_as_uint(x);
  u += 0x7fff + ((u >> 16) & 1);          // RNE
  return (unsigned short)(u >> 16);
}

// 16B-per-lane async global->LDS. LDS dest is wave-uniform base + lane*16.
__device__ __forceinline__ void gl_lds16(const void* g, void* lds) {
  __builtin_amdgcn_global_load_lds(
      (__attribute__((address_space(1))) void*)(unsigned long long)(g),
      (__attribute__((address_space(3))) void*)(lds),
      16, 0, 0);
}

// ---------------------------------------------------------------------------
// Pass 1 (v5): x (NCHW f32) -> xp_t (padded NHWC bf16, WP=58) + GAP partials.
// bf16 LDS transpose buffer (stride 132: b64-aligned for c4%4==0, halves LDS
// bytes); output loop reads ushort4 directly (no per-element f2bf there).
// GAP sums the bf16-rounded values (error ~1e-4 through routing).
// ---------------------------------------------------------------------------
__global__ __launch_bounds__(256) void k_xpose(const float* __restrict__ x,
                                               unsigned short* __restrict__ xpt,
                                               float* __restrict__ gpart) {
  const int h = blockIdx.x, b = blockIdx.y, tid = threadIdx.x;
  __shared__ __align__(16) unsigned short tfb[56 * 132];   // 14.8 KB
  __shared__ float gp[256];
  const float4* xr4 = (const float4*)x + (size_t)b * CIN * 784;  // 784=3136/4

#pragma unroll
  for (int it = 0; it < 7; ++it) {    // 1792 float4 = 128c * 14wq
    int idx = it * 256 + tid;
    int c  = idx / 14;
    int wq = idx - c * 14;
    float4 q = xr4[(size_t)c * 784 + h * 14 + wq];
    int w0 = wq * 4;
    tfb[(w0 + 0) * 132 + c] = f2bf(q.x);
    tfb[(w0 + 1) * 132 + c] = f2bf(q.y);
    tfb[(w0 + 2) * 132 + c] = f2bf(q.z);
    tfb[(w0 + 3) * 132 + c] = f2bf(q.w);
  }
  __syncthreads();

  {                                   // GAP partial: 256 threads, 28 reads each
    int c = tid & 127, half = tid >> 7;
    float s = 0.f;
#pragma unroll
    for (int w = half * 28; w < half * 28 + 28; ++w)
      s += __uint_as_float((unsigned)tfb[w * 132 + c] << 16);
    gp[tid] = s;
  }

#pragma unroll
  for (int it = 0; it < 7; ++it) {    // 1792 ushort4 stores = 56w * 32 c-quads
    int idx = it * 256 + tid;
    int w  = idx >> 5;                // [0,56)
    int c4 = (idx & 31) << 2;         // [0,128) step 4
    ushort4 o = *(const ushort4*)(tfb + w * 132 + c4);
    *(ushort4*)(xpt + ((size_t)(b * HP + (h + 1)) * WP + (w + 1)) * CIN + c4) = o;
  }

  // halo columns 0 and 57 of this image row
  if (tid < 128) {
    size_t rb = (size_t)(b * HP + (h + 1)) * WP * CIN;
    xpt[rb + tid] = 0;
    xpt[rb + 57 * CIN + tid] = 0;
  }
  // halo rows 0 and 57 (full 58*128 ushorts each)
  if (h == 0 || h == 55) {
    int hr = (h == 0) ? 0 : 57;
    size_t rb = (size_t)(b * HP + hr) * WP * CIN;
    ushort4 z; z.x = z.y = z.z = z.w = 0;
    for (int i = tid; i < 1856; i += 256)
      *(ushort4*)(xpt + rb + i * 4) = z;
  }

  __syncthreads();
  if (tid < 128)
    gpart[((size_t)h * B_ + b) * CIN + tid] =
        (gp[tid] + gp[tid + 128]) * (1.0f / 3136.0f);
}

// ---------------------------------------------------------------------------
// Pass 2 (v2): reduce gpart -> v (in LDS), then MLP + softmax. grid=32,
// block=128.
// ---------------------------------------------------------------------------
__global__ void k_mlp(const float* __restrict__ gpart, const float* __restrict__ fc1w,
                      const float* __restrict__ fc1b, const float* __restrict__ fc2w,
                      const float* __restrict__ fc2b, float* __restrict__ aout) {
  const int b = blockIdx.x, t = threadIdx.x;
  __shared__ float vS[CIN];
  __shared__ float hid[HIDDEN];
  __shared__ float lg[KEXP];
  {
    float s = 0.f;
    for (int h = 0; h < H_; ++h) s += gpart[((size_t)h * B_ + b) * CIN + t];
    vS[t] = s;
  }
  __syncthreads();
  if (t < HIDDEN) {
    float s = fc1b[t];
    const float* wr = fc1w + t * CIN;
    for (int c = 0; c < CIN; ++c) s += vS[c] * wr[c];
    hid[t] = fmaxf(s, 0.f);
  }
  __syncthreads();
  if (t < KEXP) {
    float s = fc2b[t];
    const float* wr = fc2w + t * HIDDEN;
    for (int j = 0; j < HIDDEN; ++j) s += hid[j] * wr[j];
    lg[t] = s;
  }
  __syncthreads();
  if (t == 0) {
    float m = lg[0];
    for (int k = 1; k < KEXP; ++k) m = fmaxf(m, lg[k]);
    float e[KEXP], den = 0.f;
    for (int k = 0; k < KEXP; ++k) { e[k] = expf(lg[k] - m); den += e[k]; }
    float inv = 1.0f / den;
    for (int k = 0; k < KEXP; ++k) aout[b * KEXP + k] = e[k] * inv;
  }
}

// ---------------------------------------------------------------------------
// Pass 3 (v3): Wdyn[b][cout][kk] bf16, kk = khw*128 + cin. One block of 512
// threads per cout. Stride-9 LDS reads = 2/bank = free; coalesced stores.
// ---------------------------------------------------------------------------
__global__ __launch_bounds__(512) void k_wdyn(const float* __restrict__ aout,
                                              const float* __restrict__ bank,
                                              unsigned short* __restrict__ wdyn) {
  const int cout = blockIdx.x, tid = threadIdx.x;
  __shared__ float4 bS4[KEXP * 288];          // 36 KB
  __shared__ float aS[B_ * KEXP];             // 256 routing coeffs

  for (int idx = tid; idx < KEXP * 288; idx += 512) {
    int k = idx / 288, r = idx - k * 288;
    bS4[idx] = ((const float4*)(bank + (size_t)(k * COUT + cout) * KK))[r];
  }
  if (tid < 256) aS[tid] = aout[tid];
  __syncthreads();

  const float* bS = (const float*)bS4;
  const int lane_kk = tid & 63;
  const int sg = tid >> 6;                    // 8 groups of 4 samples
  float areg[4][KEXP];
#pragma unroll
  for (int bi = 0; bi < 4; ++bi)
#pragma unroll
    for (int k = 0; k < KEXP; ++k) areg[bi][k] = aS[(sg * 4 + bi) * KEXP + k];

  for (int it = 0; it < 18; ++it) {
    int kk  = it * 64 + lane_kk;              // [0,1152)
    int khw = kk >> 7, cin = kk & 127;
    int e   = cin * 9 + khw;
    float vv[KEXP];
#pragma unroll
    for (int k = 0; k < KEXP; ++k) vv[k] = bS[k * KK + e];
#pragma unroll
    for (int bi = 0; bi < 4; ++bi) {
      float s = 0.f;
#pragma unroll
      for (int k = 0; k < KEXP; ++k) s += areg[bi][k] * vv[k];
      wdyn[(size_t)((sg * 4 + bi) * COUT + cout) * KK + kk] = f2bf(s);
    }
  }
}

// ---------------------------------------------------------------------------
// Pass 4 (R11): 128x128 tiles, 256 thr / 4 waves (2x2, 64x64 each), 64 KB
//   double-buffered LDS -> 2 blocks/CU. MFMA = 32x32x16 bf16: per tile per
//   wave 16 b128 reads feed 16 MFMA (2x2 frag grid x 4 k-slices of 16).
//   Zig-zag (0,0)->(0,1)->(1,1)->(1,0) keeps bv0/bv1 live, afA reloaded once.
//   All 8 staging loads at the switch: stage(t+1) -> vmcnt(8) -> barrier ->
//   pure reads+MFMA -> barrier. LDS layout/swizzle identical to R10.
// ---------------------------------------------------------------------------
#define BARX()   asm volatile("s_barrier" ::: "memory")
#define WAITV8() asm volatile("s_waitcnt vmcnt(8)" ::: "memory")
#define WAITV0() asm volatile("s_waitcnt vmcnt(0)" ::: "memory")

// Stage one 16 KB half-matrix tile (128 rows x 64 k, bf16) with 4 gl_lds16
// per thread. Source offsets pre-swizzled; LDS dest linear.
__device__ __forceinline__ void stage4(const unsigned short* src, unsigned short* dbuf,
                                       const int (&off)[4], int disp, int tid) {
#pragma unroll
  for (int g = 0; g < 4; ++g)
    gl_lds16(src + off[g] + disp, dbuf + (g * 256 + tid) * 8);
}

// Load 4 k-slice fragments (one 32-row panel) from swizzled LDS.
__device__ __forceinline__ void load4(const unsigned short* base, const int (&pc)[4],
                                      v8bf (&f)[4]) {
#pragma unroll
  for (int ks = 0; ks < 4; ++ks)
    f[ks] = *(const v8bf*)(base + pc[ks]);
}

__device__ __forceinline__ void mfma4(const v8bf (&a)[4], const v8bf (&b)[4], v16f& acc) {
  __builtin_amdgcn_s_setprio(1);
#pragma unroll
  for (int ks = 0; ks < 4; ++ks)
    acc = __builtin_amdgcn_mfma_f32_32x32x16_bf16(a[ks], b[ks], acc, 0, 0, 0);
  __builtin_amdgcn_s_setprio(0);
}

__global__ __launch_bounds__(256, 2) void k_conv128(const unsigned short* __restrict__ wdyn,
                                                    const unsigned short* __restrict__ xpt,
                                                    float* __restrict__ out) {
  extern __shared__ unsigned short sh[];
  unsigned short* A0 = sh;              // 16 KB each
  unsigned short* A1 = sh + 8192;
  unsigned short* B0 = sh + 16384;
  unsigned short* B1 = sh + 24576;

  // T1: sample->XCD affinity. 1600 = 8 XCDs * (4 samples * 2 mtiles * 25 ch).
  const int id  = blockIdx.x;
  const int xcd = id & 7, idx = id >> 3;         // idx 0..199
  const int bs  = idx / 50;
  const int r   = idx - bs * 50;
  const int b   = xcd * 4 + bs;
  const int bm  = r / 25;
  const int ch  = r - bm * 25;                   // 25 chunks of 128 pixels
  const int p0  = ch << 7;

  const int tid = threadIdx.x;
  const int wv = tid >> 6, l = tid & 63;
  const int l31 = l & 31, hi = l >> 5, s7 = l & 7;
  const int wr = wv >> 1, wc = wv & 1;           // 2M x 2N wave grid

  const unsigned short* wb = wdyn + ((size_t)b * COUT + bm * 128) * KK;
  const unsigned short* xb = xpt + (size_t)b * HP * WP * CIN;

  // Per-lane staging source offsets (ushort units), K-tile-invariant.
  int aoff[4], boff[4];
#pragma unroll
  for (int g = 0; g < 4; ++g) {
    int gidx = g * 256 + tid;                    // 0..1023
    int row = gidx >> 3;                         // 0..127
    int c = (gidx & 7) ^ (row & 7);              // pre-swizzled logical chunk
    aoff[g] = row * KK + c * 8;
    int p = p0 + row;
    p = p > 3135 ? 3135 : p;                     // clamp (tail chunk 24)
    int ph = p / 56, pw = p - ph * 56;
    boff[g] = (ph * WP + pw) * CIN + c * 8;
  }

  // LDS read addressing: row = wave_row_base + l31 (+32 per mi/ni frag);
  // k-chunk for k-slice ks is 2*ks + hi, XOR-swizzled by row&7 (= l&7).
  const int abase = (wr * 64 + l31) * 64;
  const int bbase = (wc * 64 + l31) * 64;
  int pc[4];
#pragma unroll
  for (int ks = 0; ks < 4; ++ks) pc[ks] = ((2 * ks + hi) ^ s7) * 8;

  v16f acc[2][2];
#pragma unroll
  for (int mi = 0; mi < 2; ++mi)
#pragma unroll
    for (int ni = 0; ni < 2; ++ni)
#pragma unroll
      for (int rr = 0; rr < 16; ++rr) acc[mi][ni][rr] = 0.f;

  // Prologue: stage K-tile 0 (khw=0 -> disp 0) into buf0, full drain once.
  stage4(wb, A0, aoff, 0, tid);
  stage4(xb, B0, boff, 0, tid);
  WAITV0();
  BARX();

  v8bf afA[4], bv0[4], bv1[4];

  for (int t = 0; t < 18; ++t) {
    const unsigned short* Ab = (t & 1) ? A1 : A0;
    const unsigned short* Bb = (t & 1) ? B1 : B0;
    unsigned short* An = (t & 1) ? A0 : A1;
    unsigned short* Bn = (t & 1) ? B0 : B1;

    // Switch: stage tile t+1 (8 loads), counted wait drains tile t's 8.
    if (t < 17) {
      int tn = t + 1;
      int khw = tn >> 1;
      int kh = (khw * 11) >> 5;                  // /3 for 0..8
      int kw = khw - 3 * kh;
      stage4(wb, An, aoff, tn * 64, tid);
      stage4(xb, Bn, boff, (kh * WP + kw) * CIN + ((tn & 1) << 6), tid);
      WAITV8();
    } else {
      WAITV0();
    }
    BARX();

    // Pure compute: zig-zag quadrants, 16 b128 reads + 16 MFMA(32x32x16).
    load4(Ab + abase, pc, afA);
    load4(Bb + bbase, pc, bv0);
    mfma4(afA, bv0, acc[0][0]);
    load4(Bb + bbase + 2048, pc, bv1);
    mfma4(afA, bv1, acc[0][1]);
    load4(Ab + abase + 2048, pc, afA);
    mfma4(afA, bv1, acc[1][1]);
    mfma4(afA, bv0, acc[1][0]);
    BARX();
  }

  // Epilogue: 32x32 C layout: col = l31, row = (reg&3) + 8*(reg>>2) + 4*hi.
#pragma unroll
  for (int mi = 0; mi < 2; ++mi)
#pragma unroll
    for (int ni = 0; ni < 2; ++ni) {
      int p = p0 + wc * 64 + ni * 32 + l31;
      if (p < HW) {
#pragma unroll
        for (int reg = 0; reg < 16; ++reg) {
          int cout = bm * 128 + wr * 64 + mi * 32 + (reg & 3) + 8 * (reg >> 2) + 4 * hi;
          out[(size_t)(b * COUT + cout) * HW + p] = acc[mi][ni][reg];
        }
      }
    }
}

// ---------------------------------------------------------------------------
// Workspace layout (~48.5 MB, all regions fully written before read):
//   [0, 917504)            gpart f32 [56][32][128]
//   [1 MB, +1024)          a f32 [32][8]
//   [2 MB, +18874368)      Wdyn bf16 [b][cout][1152]
//   [2MB+18874368, +27553792)  xp_t bf16 [b][58][58][128]
// ---------------------------------------------------------------------------
extern "C" void kernel_launch(void* const* d_in, const int* in_sizes, int n_in,
                              void* d_out, int out_size, void* d_ws, size_t ws_size,
                              hipStream_t stream) {
  const float* x    = (const float*)d_in[0];
  const float* bank = (const float*)d_in[1];
  const float* fc1w = (const float*)d_in[2];
  const float* fc1b = (const float*)d_in[3];
  const float* fc2w = (const float*)d_in[4];
  const float* fc2b = (const float*)d_in[5];
  float* out = (float*)d_out;

  char* ws = (char*)d_ws;
  float* gpart = (float*)(ws + 0);
  float* aout  = (float*)(ws + (1u << 20));
  unsigned short* wdyn = (unsigned short*)(ws + (2u << 20));
  unsigned short* xpt  = (unsigned short*)(ws + (2u << 20) + 18874368);

  static bool attr_done = false;
  if (!attr_done) {
    (void)hipFuncSetAttribute((const void*)k_conv128,
                              hipFuncAttributeMaxDynamicSharedMemorySize, 65536);
    attr_done = true;
  }

  k_xpose<<<dim3(H_, B_), 256, 0, stream>>>(x, xpt, gpart);
  k_mlp<<<dim3(B_), 128, 0, stream>>>(gpart, fc1w, fc1b, fc2w, fc2b, aout);
  k_wdyn<<<dim3(COUT), 512, 0, stream>>>(aout, bank, wdyn);
  k_conv128<<<dim3(1600), 256, 65536, stream>>>(wdyn, xpt, out);
}